// Round 1
// baseline (13440.517 us; speedup 1.0000x reference)
//
#include <hip/hip_runtime.h>
#include <math.h>

#define BATCH 16
#define LPH 128
#define TFR 1024
#define DMODEL 384
#define NHEAD 2
#define DHEAD 192
#define FDIM 1536
#define NLAYER 6
#define NMELB 80
#define CDPC 256
#define NEGV (-1e9f)

// ============================ positional encoding ============================
__global__ void posenc_kernel(float* __restrict__ pe) {
  int i = blockIdx.x * 256 + threadIdx.x;
  if (i >= TFR * DMODEL) return;
  int t = i / DMODEL, d = i - t * DMODEL;
  float f = (2.0f * (float)(d >> 1)) / (float)DMODEL;
  float ang = (float)t * powf(10000.0f, -f);
  pe[i] = (d & 1) ? cosf(ang) : sinf(ang);
}

// ============================ embedding + scaled PE ==========================
__global__ void embed_kernel(const int* __restrict__ ph, const float* __restrict__ emb,
                             const float* __restrict__ pe, const float* __restrict__ alpha,
                             float* __restrict__ x) {
  int i = blockIdx.x * 256 + threadIdx.x;
  if (i >= BATCH * LPH * DMODEL) return;
  int d = i % DMODEL;
  int bl = i / DMODEL;
  int l = bl % LPH;
  x[i] = emb[ph[bl] * DMODEL + d] + alpha[0] * pe[l * DMODEL + d];
}

// ============================ f32 tiled GEMM =================================
// C[M,N] = act(A[M,K] @ W[K,N] + bias (+res)); batched over blockIdx.z
// (W += z*wstride, bias += z*N, C += z*cstride). M % 128 == 0, K % 16 == 0.
template <bool RELU, bool HASRES>
__global__ __launch_bounds__(256) void gemm128(
    const float* __restrict__ A, const float* __restrict__ W,
    const float* __restrict__ bias, const float* __restrict__ res,
    float* __restrict__ C, int M, int N, int K, long wstride, long cstride) {
  __shared__ __align__(16) float As[16][128];
  __shared__ __align__(16) float Bs[16][128];
  const int tid = threadIdx.x;
  const int tx = tid & 15, ty = tid >> 4;
  const float* Wz = W + (long)blockIdx.z * wstride;
  const float* bz = bias + (long)blockIdx.z * N;
  float* Cz = C + (long)blockIdx.z * cstride;
  const int row0 = blockIdx.y * 128;
  const int col0 = blockIdx.x * 128;
  float acc[8][8];
#pragma unroll
  for (int i = 0; i < 8; i++)
#pragma unroll
    for (int j = 0; j < 8; j++) acc[i][j] = 0.f;

  for (int k0 = 0; k0 < K; k0 += 16) {
#pragma unroll
    for (int i = 0; i < 2; i++) {
      int fi = tid + i * 256;       // 0..511 (512 float4 = 128x16 tile)
      int ar = fi >> 2;             // 0..127
      int ac = (fi & 3) * 4;        // 0,4,8,12
      float4 va = *(const float4*)&A[(long)(row0 + ar) * K + k0 + ac];
      As[ac + 0][ar] = va.x; As[ac + 1][ar] = va.y;
      As[ac + 2][ar] = va.z; As[ac + 3][ar] = va.w;
    }
#pragma unroll
    for (int i = 0; i < 2; i++) {
      int fi = tid + i * 256;
      int br = fi >> 5;             // 0..15
      int bc = (fi & 31) * 4;       // 0..124
      int gc = col0 + bc;
      float4 vb;
      if (gc + 3 < N) {
        vb = *(const float4*)&Wz[(long)(k0 + br) * N + gc];
      } else {
        vb.x = (gc + 0 < N) ? Wz[(long)(k0 + br) * N + gc + 0] : 0.f;
        vb.y = (gc + 1 < N) ? Wz[(long)(k0 + br) * N + gc + 1] : 0.f;
        vb.z = (gc + 2 < N) ? Wz[(long)(k0 + br) * N + gc + 2] : 0.f;
        vb.w = (gc + 3 < N) ? Wz[(long)(k0 + br) * N + gc + 3] : 0.f;
      }
      *(float4*)&Bs[br][bc] = vb;
    }
    __syncthreads();
#pragma unroll
    for (int kk = 0; kk < 16; kk++) {
      float a[8], b[8];
      *(float4*)&a[0] = *(const float4*)&As[kk][ty * 8];
      *(float4*)&a[4] = *(const float4*)&As[kk][ty * 8 + 4];
      *(float4*)&b[0] = *(const float4*)&Bs[kk][tx * 8];
      *(float4*)&b[4] = *(const float4*)&Bs[kk][tx * 8 + 4];
#pragma unroll
      for (int i = 0; i < 8; i++)
#pragma unroll
        for (int j = 0; j < 8; j++) acc[i][j] = fmaf(a[i], b[j], acc[i][j]);
    }
    __syncthreads();
  }
#pragma unroll
  for (int i = 0; i < 8; i++) {
    int r = row0 + ty * 8 + i;
#pragma unroll
    for (int j = 0; j < 8; j++) {
      int c = col0 + tx * 8 + j;
      if (c < N) {
        float vv = acc[i][j] + bz[c];
        if (HASRES) vv += res[(long)r * N + c];
        if (RELU) vv = fmaxf(vv, 0.f);
        Cz[(long)r * N + c] = vv;
      }
    }
  }
}

// ============================ LayerNorm (in-place, 1 block/row) ==============
__global__ __launch_bounds__(256) void ln_kernel(float* __restrict__ x,
                                                 const float* __restrict__ gamma,
                                                 const float* __restrict__ beta, int C) {
  long row = blockIdx.x;
  float* xr = x + row * C;
  int tid = threadIdx.x;
  float e0 = 0.f, e1 = 0.f;
  float s1 = 0.f, s2 = 0.f;
  if (tid < C) { e0 = xr[tid]; s1 += e0; s2 += e0 * e0; }
  if (tid + 256 < C) { e1 = xr[tid + 256]; s1 += e1; s2 += e1 * e1; }
#pragma unroll
  for (int off = 32; off > 0; off >>= 1) {
    s1 += __shfl_down(s1, off);
    s2 += __shfl_down(s2, off);
  }
  __shared__ float w1[4], w2[4];
  if ((tid & 63) == 0) { w1[tid >> 6] = s1; w2[tid >> 6] = s2; }
  __syncthreads();
  float S1 = w1[0] + w1[1] + w1[2] + w1[3];
  float S2 = w2[0] + w2[1] + w2[2] + w2[3];
  float mean = S1 / C;
  float var = S2 / C - mean * mean;
  float rstd = rsqrtf(var + 1e-6f);
  if (tid < C) xr[tid] = (e0 - mean) * rstd * gamma[tid] + beta[tid];
  if (tid + 256 < C) xr[tid + 256] = (e1 - mean) * rstd * gamma[tid + 256] + beta[tid + 256];
}

// ============================ flash attention (f32) ==========================
// q,k,v,o: [B,S,D] with heads along D (q[b,h,s,:] = buf[b,s,h*DHEAD..]).
// maskv: [B,S] floats, 1.0 = masked key (or nullptr). Q pre-scaled by 1/sqrt(dh).
#define FQT 32
#define FKT 16
#define FSTR 196   // padded row stride (floats): breaks bank alignment, 16B-aligned rows

__global__ __launch_bounds__(256) void flash_kernel(
    const float* __restrict__ q, const float* __restrict__ k, const float* __restrict__ v,
    const float* __restrict__ maskv, float* __restrict__ o, int S) {
  __shared__ __align__(16) float Qs[FQT][FSTR];
  __shared__ __align__(16) float Ks[FKT][FSTR];
  __shared__ __align__(16) float Vs[FKT][FSTR];
  __shared__ float Ss[FQT][FKT + 1];
  __shared__ float mrow[FQT], lrow[FQT], arow[FQT];
  const int tid = threadIdx.x;
  const int b = blockIdx.z, h = blockIdx.y;
  const int q0 = blockIdx.x * FQT;
  const long base = ((long)b * S) * DMODEL + h * DHEAD;
  const float scale = rsqrtf((float)DHEAD);

  for (int i4 = tid; i4 < FQT * (DHEAD / 4); i4 += 256) {
    int r = i4 / (DHEAD / 4), c4 = (i4 % (DHEAD / 4)) * 4;
    float4 vv = *(const float4*)&q[base + (long)(q0 + r) * DMODEL + c4];
    vv.x *= scale; vv.y *= scale; vv.z *= scale; vv.w *= scale;
    *(float4*)&Qs[r][c4] = vv;
  }
  if (tid < FQT) { mrow[tid] = -1e30f; lrow[tid] = 0.f; }
  float acc[24];
#pragma unroll
  for (int i = 0; i < 24; i++) acc[i] = 0.f;
  const int r_pv = tid >> 3;
  const int c_pv = (tid & 7) * 24;
  const int r_s = (tid >> 4) * 2;
  const int c_s = tid & 15;

  for (int kt = 0; kt < S; kt += FKT) {
    for (int i4 = tid; i4 < FKT * (DHEAD / 4); i4 += 256) {
      int r = i4 / (DHEAD / 4), c4 = (i4 % (DHEAD / 4)) * 4;
      *(float4*)&Ks[r][c4] = *(const float4*)&k[base + (long)(kt + r) * DMODEL + c4];
      *(float4*)&Vs[r][c4] = *(const float4*)&v[base + (long)(kt + r) * DMODEL + c4];
    }
    __syncthreads();
    {
      float s0 = 0.f, s1v = 0.f;
      for (int kk = 0; kk < DHEAD; kk += 4) {
        float4 ka = *(const float4*)&Ks[c_s][kk];
        float4 qa = *(const float4*)&Qs[r_s][kk];
        float4 qb = *(const float4*)&Qs[r_s + 1][kk];
        s0 = fmaf(qa.x, ka.x, s0); s0 = fmaf(qa.y, ka.y, s0);
        s0 = fmaf(qa.z, ka.z, s0); s0 = fmaf(qa.w, ka.w, s0);
        s1v = fmaf(qb.x, ka.x, s1v); s1v = fmaf(qb.y, ka.y, s1v);
        s1v = fmaf(qb.z, ka.z, s1v); s1v = fmaf(qb.w, ka.w, s1v);
      }
      if (maskv != nullptr) {
        float mk = maskv[(long)b * S + kt + c_s] * NEGV;
        s0 += mk; s1v += mk;
      }
      Ss[r_s][c_s] = s0;
      Ss[r_s + 1][c_s] = s1v;
    }
    __syncthreads();
    if (tid < FQT) {
      int r = tid;
      float rmax = Ss[r][0];
      for (int j = 1; j < FKT; j++) rmax = fmaxf(rmax, Ss[r][j]);
      float mold = mrow[r];
      float mnew = fmaxf(mold, rmax);
      float al = __expf(mold - mnew);
      float rsum = 0.f;
      for (int j = 0; j < FKT; j++) {
        float p = __expf(Ss[r][j] - mnew);
        Ss[r][j] = p;
        rsum += p;
      }
      lrow[r] = lrow[r] * al + rsum;
      mrow[r] = mnew;
      arow[r] = al;
    }
    __syncthreads();
    {
      float al = arow[r_pv];
#pragma unroll
      for (int i = 0; i < 24; i++) acc[i] *= al;
      for (int j = 0; j < FKT; j++) {
        float p = Ss[r_pv][j];
#pragma unroll
        for (int c4 = 0; c4 < 24; c4 += 4) {
          float4 vv = *(const float4*)&Vs[j][c_pv + c4];
          acc[c4 + 0] = fmaf(p, vv.x, acc[c4 + 0]);
          acc[c4 + 1] = fmaf(p, vv.y, acc[c4 + 1]);
          acc[c4 + 2] = fmaf(p, vv.z, acc[c4 + 2]);
          acc[c4 + 3] = fmaf(p, vv.w, acc[c4 + 3]);
        }
      }
    }
    __syncthreads();
  }
  float inv = 1.0f / lrow[r_pv];
  long obase = base + (long)(q0 + r_pv) * DMODEL + c_pv;
#pragma unroll
  for (int c4 = 0; c4 < 24; c4 += 4) {
    float4 vv;
    vv.x = acc[c4 + 0] * inv; vv.y = acc[c4 + 1] * inv;
    vv.z = acc[c4 + 2] * inv; vv.w = acc[c4 + 3] * inv;
    *(float4*)&o[obase + c4] = vv;
  }
}

// ============================ K=3 SAME conv + bias + relu ====================
// x: [B,LPH,CIN], w: [3,CIN,CDPC], out: [B,LPH,CDPC]. blockDim = CDPC = 256.
template <int CIN>
__global__ __launch_bounds__(256) void conv3_kernel(
    const float* __restrict__ x, const float* __restrict__ w,
    const float* __restrict__ bias, float* __restrict__ out) {
  __shared__ float xs[34][CIN];
  const int b = blockIdx.y;
  const int l0 = blockIdx.x * 32;
  const int co = threadIdx.x;
  for (int idx = threadIdx.x; idx < 34 * CIN; idx += 256) {
    int r = idx / CIN, c = idx - r * CIN;
    int gl = l0 + r - 1;
    xs[r][c] = (gl >= 0 && gl < LPH) ? x[((long)b * LPH + gl) * CIN + c] : 0.f;
  }
  __syncthreads();
  float acc[32];
#pragma unroll
  for (int i = 0; i < 32; i++) acc[i] = 0.f;
  for (int kk = 0; kk < 3; kk++)
    for (int ci = 0; ci < CIN; ci++) {
      float wv = w[((long)kk * CIN + ci) * CDPC + co];
#pragma unroll
      for (int l = 0; l < 32; l++) acc[l] = fmaf(xs[l + kk][ci], wv, acc[l]);
    }
  float bv = bias[co];
#pragma unroll
  for (int l = 0; l < 32; l++)
    out[((long)b * LPH + l0 + l) * CDPC + co] = fmaxf(acc[l] + bv, 0.f);
}

// ============================ duration projection ============================
__global__ void dpout_kernel(const float* __restrict__ d2, const float* __restrict__ w,
                             const float* __restrict__ bb, float* __restrict__ out) {
  int wv = threadIdx.x >> 6, lane = threadIdx.x & 63;
  int row = blockIdx.x * 4 + wv;
  const float* xr = d2 + (long)row * CDPC;
  float s = 0.f;
  for (int c = lane; c < CDPC; c += 64) s = fmaf(xr[c], w[c], s);
#pragma unroll
  for (int off = 32; off > 0; off >>= 1) s += __shfl_down(s, off);
  if (lane == 0) out[row] = s + bb[0];
}

// ============================ length regulator ===============================
__global__ void regulator_kernel(const int* __restrict__ durations, int* __restrict__ idx,
                                 float* __restrict__ maskv) {
  __shared__ int cum[LPH];
  __shared__ int total;
  int b = blockIdx.x;
  if (threadIdx.x == 0) {
    int s = 0;
    for (int j = 0; j < LPH; j++) { s += durations[b * LPH + j]; cum[j] = s; }
    total = s;
  }
  __syncthreads();
  for (int t = threadIdx.x; t < TFR; t += blockDim.x) {
    int cnt = 0;
    for (int j = 0; j < LPH; j++) cnt += (cum[j] <= t) ? 1 : 0;
    if (cnt > LPH - 1) cnt = LPH - 1;
    idx[b * TFR + t] = cnt;
    maskv[b * TFR + t] = (t < total) ? 0.f : 1.f;   // 1 = masked
  }
}

// gather expanded states, apply valid mask, add scaled PE
__global__ void gather_kernel(const float* __restrict__ h, const int* __restrict__ idx,
                              const float* __restrict__ maskv, const float* __restrict__ pe,
                              const float* __restrict__ alpha, float* __restrict__ y) {
  long i = (long)blockIdx.x * 256 + threadIdx.x;
  if (i >= (long)BATCH * TFR * DMODEL) return;
  int d = (int)(i % DMODEL);
  long bt = i / DMODEL;
  int t = (int)(bt % TFR);
  long b = bt / TFR;
  float valid = 1.0f - maskv[bt];
  y[i] = h[((long)b * LPH + idx[bt]) * DMODEL + d] * valid + alpha[0] * pe[t * DMODEL + d];
}

// ============================ launcher =======================================
extern "C" void kernel_launch(void* const* d_in, const int* in_sizes, int n_in,
                              void* d_out, int out_size, void* d_ws, size_t ws_size,
                              hipStream_t stream) {
  const int* phonemes = (const int*)d_in[0];
  const int* durations = (const int*)d_in[1];
  const float* embedw = (const float*)d_in[2];
  const float* alpha_enc = (const float*)d_in[3];
  const float* alpha_dec = (const float*)d_in[4];
  const float* enc_attn_w = (const float*)d_in[5];
  const float* enc_attn_b = (const float*)d_in[6];
  const float* enc_ffn_w1 = (const float*)d_in[7];
  const float* enc_ffn_b1 = (const float*)d_in[8];
  const float* enc_ffn_w2 = (const float*)d_in[9];
  const float* enc_ffn_b2 = (const float*)d_in[10];
  const float* enc_ln = (const float*)d_in[11];
  const float* dec_attn_w = (const float*)d_in[12];
  const float* dec_attn_b = (const float*)d_in[13];
  const float* dec_ffn_w1 = (const float*)d_in[14];
  const float* dec_ffn_b1 = (const float*)d_in[15];
  const float* dec_ffn_w2 = (const float*)d_in[16];
  const float* dec_ffn_b2 = (const float*)d_in[17];
  const float* dec_ln = (const float*)d_in[18];
  const float* dp_conv1_w = (const float*)d_in[19];
  const float* dp_conv1_b = (const float*)d_in[20];
  const float* dp_conv2_w = (const float*)d_in[21];
  const float* dp_conv2_b = (const float*)d_in[22];
  const float* dp_ln = (const float*)d_in[23];
  const float* dp_out_w = (const float*)d_in[24];
  const float* dp_out_b = (const float*)d_in[25];
  const float* mel_w = (const float*)d_in[26];
  const float* mel_b = (const float*)d_in[27];

  // workspace layout (floats). Total: 6*NX + 2*B*T = 37,781,504 floats = 151.1 MB
  const size_t NX = (size_t)BATCH * TFR * DMODEL;  // 6,291,456
  float* ws = (float*)d_ws;
  float* X0 = ws;            // x (encoder) / ffn-mid partner (decoder)
  float* X1 = X0 + NX;       // mid (encoder) / x (decoder)
  float* S0 = X1 + NX;       // scratch: q / ffn-mid span start
  float* S1 = S0 + NX;       // k
  float* S2 = S1 + NX;       // v
  float* S3 = S2 + NX;       // attn out
  float* PE = S3 + 2097152;  // overlay in unused tail of S3 (dead before decoder FFN)
  float* DP1 = S1;           // overlay (S free during duration-predictor phase)
  float* DP2 = S1 + (size_t)BATCH * LPH * CDPC;
  float* MASKD = S3 + NX;    // [B,T] decoder key mask, lives past S region
  int* IDX = (int*)(MASKD + (size_t)BATCH * TFR);

  const int Me = BATCH * LPH;   // 2048
  const int Md = BATCH * TFR;   // 16384
  const long DD = (long)DMODEL * DMODEL;

  posenc_kernel<<<(TFR * DMODEL + 255) / 256, 256, 0, stream>>>(PE);
  embed_kernel<<<(Me * DMODEL + 255) / 256, 256, 0, stream>>>(phonemes, embedw, PE, alpha_enc, X0);

  // -------- phoneme encoder (x lives in X0) --------
  for (int i = 0; i < NLAYER; i++) {
    const float* aw = enc_attn_w + (size_t)i * 4 * DD;
    const float* ab = enc_attn_b + (size_t)i * 4 * DMODEL;
    gemm128<false, false><<<dim3(DMODEL / 128, Me / 128, 3), 256, 0, stream>>>(
        X0, aw, ab, nullptr, S0, Me, DMODEL, DMODEL, DD, (long)NX);
    flash_kernel<<<dim3(LPH / FQT, NHEAD, BATCH), 256, 0, stream>>>(S0, S1, S2, nullptr, S3, LPH);
    gemm128<false, true><<<dim3(DMODEL / 128, Me / 128, 1), 256, 0, stream>>>(
        S3, aw + 3 * DD, ab + 3 * DMODEL, X0, X1, Me, DMODEL, DMODEL, 0, 0);
    ln_kernel<<<Me, 256, 0, stream>>>(X1, enc_ln + ((size_t)(i * 2 + 0) * 2 + 0) * DMODEL,
                                      enc_ln + ((size_t)(i * 2 + 0) * 2 + 1) * DMODEL, DMODEL);
    gemm128<true, false><<<dim3(FDIM / 128, Me / 128, 1), 256, 0, stream>>>(
        X1, enc_ffn_w1 + (size_t)i * DMODEL * FDIM, enc_ffn_b1 + (size_t)i * FDIM, nullptr, S0,
        Me, FDIM, DMODEL, 0, 0);
    gemm128<false, true><<<dim3(DMODEL / 128, Me / 128, 1), 256, 0, stream>>>(
        S0, enc_ffn_w2 + (size_t)i * FDIM * DMODEL, enc_ffn_b2 + (size_t)i * DMODEL, X1, X0,
        Me, DMODEL, FDIM, 0, 0);
    ln_kernel<<<Me, 256, 0, stream>>>(X0, enc_ln + ((size_t)(i * 2 + 1) * 2 + 0) * DMODEL,
                                      enc_ln + ((size_t)(i * 2 + 1) * 2 + 1) * DMODEL, DMODEL);
  }

  // -------- duration predictor (h = X0) --------
  conv3_kernel<DMODEL><<<dim3(LPH / 32, BATCH), 256, 0, stream>>>(X0, dp_conv1_w, dp_conv1_b, DP1);
  ln_kernel<<<Me, 256, 0, stream>>>(DP1, dp_ln + 0 * CDPC, dp_ln + 1 * CDPC, CDPC);
  conv3_kernel<CDPC><<<dim3(LPH / 32, BATCH), 256, 0, stream>>>(DP1, dp_conv2_w, dp_conv2_b, DP2);
  ln_kernel<<<Me, 256, 0, stream>>>(DP2, dp_ln + 2 * CDPC, dp_ln + 3 * CDPC, CDPC);
  float* durout = (float*)d_out + (size_t)Md * NMELB;
  dpout_kernel<<<Me / 4, 256, 0, stream>>>(DP2, dp_out_w, dp_out_b, durout);

  // -------- length regulator --------
  regulator_kernel<<<BATCH, 256, 0, stream>>>(durations, IDX, MASKD);
  gather_kernel<<<(int)((NX + 255) / 256), 256, 0, stream>>>(X0, IDX, MASKD, PE, alpha_dec, X1);

  // -------- mel decoder (x lives in X1) --------
  for (int i = 0; i < NLAYER; i++) {
    const float* aw = dec_attn_w + (size_t)i * 4 * DD;
    const float* ab = dec_attn_b + (size_t)i * 4 * DMODEL;
    gemm128<false, false><<<dim3(DMODEL / 128, Md / 128, 3), 256, 0, stream>>>(
        X1, aw, ab, nullptr, S0, Md, DMODEL, DMODEL, DD, (long)NX);
    flash_kernel<<<dim3(TFR / FQT, NHEAD, BATCH), 256, 0, stream>>>(S0, S1, S2, MASKD, S3, TFR);
    gemm128<false, true><<<dim3(DMODEL / 128, Md / 128, 1), 256, 0, stream>>>(
        S3, aw + 3 * DD, ab + 3 * DMODEL, X1, X0, Md, DMODEL, DMODEL, 0, 0);
    ln_kernel<<<Md, 256, 0, stream>>>(X0, dec_ln + ((size_t)(i * 2 + 0) * 2 + 0) * DMODEL,
                                      dec_ln + ((size_t)(i * 2 + 0) * 2 + 1) * DMODEL, DMODEL);
    gemm128<true, false><<<dim3(FDIM / 128, Md / 128, 1), 256, 0, stream>>>(
        X0, dec_ffn_w1 + (size_t)i * DMODEL * FDIM, dec_ffn_b1 + (size_t)i * FDIM, nullptr, S0,
        Md, FDIM, DMODEL, 0, 0);
    gemm128<false, true><<<dim3(DMODEL / 128, Md / 128, 1), 256, 0, stream>>>(
        S0, dec_ffn_w2 + (size_t)i * FDIM * DMODEL, dec_ffn_b2 + (size_t)i * DMODEL, X0, X1,
        Md, DMODEL, FDIM, 0, 0);
    ln_kernel<<<Md, 256, 0, stream>>>(X1, dec_ln + ((size_t)(i * 2 + 1) * 2 + 0) * DMODEL,
                                      dec_ln + ((size_t)(i * 2 + 1) * 2 + 1) * DMODEL, DMODEL);
  }

  // -------- mel projection --------
  gemm128<false, false><<<dim3(1, Md / 128, 1), 256, 0, stream>>>(
      X1, mel_w, mel_b, nullptr, (float*)d_out, Md, NMELB, DMODEL, 0, 0);
}

// Round 2
// 3671.579 us; speedup vs baseline: 3.6607x; 3.6607x over previous
//
#include <hip/hip_runtime.h>
#include <math.h>

#define BATCH 16
#define LPH 128
#define TFR 1024
#define DMODEL 384
#define FDIM 1536
#define NLAYER 6
#define NMELB 80
#define CDPC 256
#define NEGV (-1e9f)

typedef unsigned short u16;
typedef __attribute__((ext_vector_type(8))) short short8;
typedef __attribute__((ext_vector_type(4))) float f32x4;

__device__ __forceinline__ float b2f(u16 u) {
  return __uint_as_float(((unsigned)u) << 16);
}
__device__ __forceinline__ u16 f2b(float f) {
  unsigned x = __float_as_uint(f);
  return (u16)((x + 0x7fffu + ((x >> 16) & 1u)) >> 16);
}

#define GLOAD16(gp, lp)                                                                   \
  __builtin_amdgcn_global_load_lds((const __attribute__((address_space(1))) void*)(gp),   \
                                   (__attribute__((address_space(3))) void*)(lp), 16, 0, 0)

#define FBIAS 1
#define FRES 2
#define FRELU 4
#define FOB16 8
#define FVT 16

// ===================== bf16 MFMA GEMM, 128x128 tile, BK=32 ===================
// C[M,N] = act(A[M,K] @ Bt[N,K]^T + bias (+res)). A,Bt bf16 row-major (k-contig).
// Per-z offsets: off = (z/zdiv)*s0 + (z%zdiv)*s1 for A,B,C. M%128==0, K%32==0.
// FVT: for z==2 (V of QKV), store transposed into VtP[(b*2+h)*256+d][s] (bf16).
template <int FL>
__global__ __launch_bounds__(256) void bgemm(
    const u16* __restrict__ A, const u16* __restrict__ Bt,
    const float* __restrict__ bias, const float* __restrict__ res,
    void* __restrict__ Cv, u16* __restrict__ VtP,
    int N, int K, int lda, int ldb, int ldc,
    int zdiv, long az0, long az1, long bz0, long bz1, long cz0, long cz1, int S) {
  __shared__ __align__(16) u16 As[4096];
  __shared__ __align__(16) u16 Bs[4096];
  const int tid = threadIdx.x;
  const int wave = tid >> 6, lane = tid & 63;
  const int wm = wave >> 1, wn = wave & 1;
  const int lrow = lane & 15, lk = lane >> 4;
  const int z = blockIdx.z;
  const int zq = z / zdiv, zr = z - zq * zdiv;
  const long offA = (long)zq * az0 + (long)zr * az1;
  const long offB = (long)zq * bz0 + (long)zr * bz1;
  const long offC = (long)zq * cz0 + (long)zr * cz1;
  const int row0 = blockIdx.y * 128;
  const int col0 = blockIdx.x * 128;

  // staging: 8 x 1KB insts per tile; wave w owns insts {2w, 2w+1} for A and B
  const int sj = wave * 2;
  const int srow = lane >> 2;        // 0..15
  const int skc = (lane & 3) * 8;    // ushort offset in k
  const u16* gA = A + offA + (long)(row0 + sj * 16 + srow) * lda + skc;
  const u16* gB = Bt + offB + (long)(col0 + sj * 16 + srow) * ldb + skc;
  u16* lA = As + sj * 512;
  u16* lB = Bs + sj * 512;
  const long ldak = 16L * lda;
  const long ldbk = 16L * ldb;

  f32x4 acc[4][4];
  const f32x4 zero4 = {0.f, 0.f, 0.f, 0.f};
#pragma unroll
  for (int i = 0; i < 4; i++)
#pragma unroll
    for (int j = 0; j < 4; j++) acc[i][j] = zero4;

  const int aoff = (wm * 64 + lrow) * 32 + lk * 8;
  const int boff = (wn * 64 + lrow) * 32 + lk * 8;

  for (int k0 = 0; k0 < K; k0 += 32) {
    GLOAD16(gA, lA);
    GLOAD16(gA + ldak, lA + 512);
    GLOAD16(gB, lB);
    GLOAD16(gB + ldbk, lB + 512);
    gA += 32; gB += 32;
    __syncthreads();   // drains vmcnt(0): staged data visible
    short8 av[4], bv[4];
#pragma unroll
    for (int mi = 0; mi < 4; mi++) av[mi] = *(const short8*)&As[aoff + mi * 512];
#pragma unroll
    for (int ni = 0; ni < 4; ni++) bv[ni] = *(const short8*)&Bs[boff + ni * 512];
#pragma unroll
    for (int mi = 0; mi < 4; mi++)
#pragma unroll
      for (int ni = 0; ni < 4; ni++)
        acc[mi][ni] = __builtin_amdgcn_mfma_f32_16x16x32_bf16(av[mi], bv[ni], acc[mi][ni], 0, 0, 0);
    __syncthreads();   // before next-iter staging overwrites LDS
  }

  const float* bz = (FL & FBIAS) ? bias + (long)z * N : nullptr;
  if ((FL & FVT) && z == 2) {
    // transposed V store: Vt[(b*2+h)*256 + d][s]
#pragma unroll
    for (int mi = 0; mi < 4; mi++) {
      long rg = row0 + wm * 64 + lk * 4 + (long)mi * 16;
      int bb = (int)(rg / S);
      int ss = (int)(rg % S);
#pragma unroll
      for (int ni = 0; ni < 4; ni++) {
        int c = col0 + wn * 64 + ni * 16 + lrow;
        int hh = c / 192, dd = c - hh * 192;
        float bi = bz[c];
        ushort4 o;
        o.x = f2b(acc[mi][ni][0] + bi);
        o.y = f2b(acc[mi][ni][1] + bi);
        o.z = f2b(acc[mi][ni][2] + bi);
        o.w = f2b(acc[mi][ni][3] + bi);
        *(ushort4*)&VtP[((long)(bb * 2 + hh) * 256 + dd) * S + ss] = o;
      }
    }
    return;
  }
  float* Cf = (float*)Cv + offC;
  u16* Cb = (u16*)Cv + offC;
  const float* resz = (FL & FRES) ? res + offC : nullptr;
#pragma unroll
  for (int mi = 0; mi < 4; mi++) {
    long rbase = row0 + wm * 64 + lk * 4 + (long)mi * 16;
#pragma unroll
    for (int ni = 0; ni < 4; ni++) {
      int c = col0 + wn * 64 + ni * 16 + lrow;
      if (c < N) {
        float bi = (FL & FBIAS) ? bz[c] : 0.f;
#pragma unroll
        for (int rr = 0; rr < 4; rr++) {
          float vv = acc[mi][ni][rr] + bi;
          if (FL & FRES) vv += resz[(rbase + rr) * (long)ldc + c];
          if (FL & FRELU) vv = fmaxf(vv, 0.f);
          if (FL & FOB16) Cb[(rbase + rr) * (long)ldc + c] = f2b(vv);
          else Cf[(rbase + rr) * (long)ldc + c] = vv;
        }
      }
    }
  }
}

// ============== weight convert+transpose: [K,N] f32 -> [N,K] bf16 ============
__global__ void wconv_t(const float* __restrict__ src, u16* __restrict__ dst, int K, int N) {
  __shared__ float t[32][33];
  long mb = blockIdx.z;
  src += mb * (long)K * N;
  dst += mb * (long)K * N;
  int n0 = blockIdx.x * 32, k0 = blockIdx.y * 32;
  int tx = threadIdx.x, ty = threadIdx.y;
#pragma unroll
  for (int i = 0; i < 4; i++) {
    int r = ty + i * 8;
    t[r][tx] = src[(long)(k0 + r) * N + n0 + tx];
  }
  __syncthreads();
#pragma unroll
  for (int i = 0; i < 4; i++) {
    int r = ty + i * 8;
    dst[(long)(n0 + r) * K + k0 + tx] = f2b(t[tx][r]);
  }
}

// ===================== softmax over bf16 score rows ==========================
// P: rows of length S (bf16, in-place). mask: [b][S] (1.0 = masked) or null.
// One wave per row, 4 rows/block. NV = S/64.
template <int NV>
__global__ __launch_bounds__(256) void softmax_bf16(u16* __restrict__ P,
                                                    const float* __restrict__ mask, int S) {
  const int wave = threadIdx.x >> 6, lane = threadIdx.x & 63;
  const long row = (long)blockIdx.x * 4 + wave;
  u16* pr = P + row * S;
  const int z = (int)(row / S);
  const float* mrow = mask ? mask + (long)(z >> 1) * S : nullptr;
  const float scale = 0.0721687836f;  // 1/sqrt(192)
  float v[NV];
  if (NV == 16) {
    short8 u0 = *(const short8*)&pr[lane * 16];
    short8 u1 = *(const short8*)&pr[lane * 16 + 8];
#pragma unroll
    for (int j = 0; j < 8; j++) {
      v[j] = b2f((u16)u0[j]);
      v[j + 8] = b2f((u16)u1[j]);
    }
  } else {
#pragma unroll
    for (int i = 0; i < NV; i++) v[i] = b2f(pr[lane * NV + i]);
  }
  float mx = -3e38f;
#pragma unroll
  for (int i = 0; i < NV; i++) {
    float mval = mrow ? mrow[lane * NV + i] * NEGV : 0.f;
    v[i] = v[i] * scale + mval;
    mx = fmaxf(mx, v[i]);
  }
  for (int off = 32; off; off >>= 1) mx = fmaxf(mx, __shfl_xor(mx, off));
  float sum = 0.f;
#pragma unroll
  for (int i = 0; i < NV; i++) {
    v[i] = __expf(v[i] - mx);
    sum += v[i];
  }
  for (int off = 32; off; off >>= 1) sum += __shfl_xor(sum, off);
  float inv = 1.f / sum;
  if (NV == 16) {
    short8 s0, s1;
#pragma unroll
    for (int j = 0; j < 8; j++) {
      s0[j] = (short)f2b(v[j] * inv);
      s1[j] = (short)f2b(v[j + 8] * inv);
    }
    *(short8*)&pr[lane * 16] = s0;
    *(short8*)&pr[lane * 16 + 8] = s1;
  } else {
#pragma unroll
    for (int i = 0; i < NV; i++) pr[lane * NV + i] = f2b(v[i] * inv);
  }
}

// ============================ positional encoding ============================
__global__ void posenc_kernel(float* __restrict__ pe) {
  int i = blockIdx.x * 256 + threadIdx.x;
  if (i >= TFR * DMODEL) return;
  int t = i / DMODEL, d = i - t * DMODEL;
  float f = (2.0f * (float)(d >> 1)) / (float)DMODEL;
  float ang = (float)t * powf(10000.0f, -f);
  pe[i] = (d & 1) ? cosf(ang) : sinf(ang);
}

// ===================== embedding + scaled PE (f32 + bf16) ====================
__global__ void embed_kernel(const int* __restrict__ ph, const float* __restrict__ emb,
                             const float* __restrict__ pe, const float* __restrict__ alpha,
                             float* __restrict__ x, u16* __restrict__ xb) {
  int i = blockIdx.x * 256 + threadIdx.x;
  if (i >= BATCH * LPH * DMODEL) return;
  int d = i % DMODEL;
  int bl = i / DMODEL;
  int l = bl % LPH;
  float v = emb[ph[bl] * DMODEL + d] + alpha[0] * pe[l * DMODEL + d];
  x[i] = v;
  xb[i] = f2b(v);
}

// ================= LayerNorm: in-place or to outf; optional bf16 =============
__global__ __launch_bounds__(256) void ln2_kernel(float* __restrict__ x,
                                                  const float* __restrict__ gamma,
                                                  const float* __restrict__ beta, int C,
                                                  float* __restrict__ outf,
                                                  u16* __restrict__ outb) {
  long row = blockIdx.x;
  float* xr = x + row * C;
  int tid = threadIdx.x;
  float e0 = 0.f, e1 = 0.f;
  float s1 = 0.f, s2 = 0.f;
  if (tid < C) { e0 = xr[tid]; s1 += e0; s2 += e0 * e0; }
  if (tid + 256 < C) { e1 = xr[tid + 256]; s1 += e1; s2 += e1 * e1; }
#pragma unroll
  for (int off = 32; off > 0; off >>= 1) {
    s1 += __shfl_down(s1, off);
    s2 += __shfl_down(s2, off);
  }
  __shared__ float w1[4], w2[4];
  if ((tid & 63) == 0) { w1[tid >> 6] = s1; w2[tid >> 6] = s2; }
  __syncthreads();
  float S1 = w1[0] + w1[1] + w1[2] + w1[3];
  float S2 = w2[0] + w2[1] + w2[2] + w2[3];
  float mean = S1 / C;
  float var = S2 / C - mean * mean;
  float rstd = rsqrtf(var + 1e-6f);
  float* tf = outf ? outf + row * C : xr;
  if (tid < C) {
    float v = (e0 - mean) * rstd * gamma[tid] + beta[tid];
    tf[tid] = v;
    if (outb) outb[row * C + tid] = f2b(v);
  }
  if (tid + 256 < C) {
    float v = (e1 - mean) * rstd * gamma[tid + 256] + beta[tid + 256];
    tf[tid + 256] = v;
    if (outb) outb[row * C + tid + 256] = f2b(v);
  }
}

// ============================ f32 tiled GEMM (mel only) ======================
template <bool RELU, bool HASRES>
__global__ __launch_bounds__(256) void gemm128(
    const float* __restrict__ A, const float* __restrict__ W,
    const float* __restrict__ bias, const float* __restrict__ res,
    float* __restrict__ C, int M, int N, int K, long wstride, long cstride) {
  __shared__ __align__(16) float As[16][128];
  __shared__ __align__(16) float Bs[16][128];
  const int tid = threadIdx.x;
  const int tx = tid & 15, ty = tid >> 4;
  const float* Wz = W + (long)blockIdx.z * wstride;
  const float* bz = bias + (long)blockIdx.z * N;
  float* Cz = C + (long)blockIdx.z * cstride;
  const int row0 = blockIdx.y * 128;
  const int col0 = blockIdx.x * 128;
  float acc[8][8];
#pragma unroll
  for (int i = 0; i < 8; i++)
#pragma unroll
    for (int j = 0; j < 8; j++) acc[i][j] = 0.f;

  for (int k0 = 0; k0 < K; k0 += 16) {
#pragma unroll
    for (int i = 0; i < 2; i++) {
      int fi = tid + i * 256;
      int ar = fi >> 2;
      int ac = (fi & 3) * 4;
      float4 va = *(const float4*)&A[(long)(row0 + ar) * K + k0 + ac];
      As[ac + 0][ar] = va.x; As[ac + 1][ar] = va.y;
      As[ac + 2][ar] = va.z; As[ac + 3][ar] = va.w;
    }
#pragma unroll
    for (int i = 0; i < 2; i++) {
      int fi = tid + i * 256;
      int br = fi >> 5;
      int bc = (fi & 31) * 4;
      int gc = col0 + bc;
      float4 vb;
      if (gc + 3 < N) {
        vb = *(const float4*)&Wz[(long)(k0 + br) * N + gc];
      } else {
        vb.x = (gc + 0 < N) ? Wz[(long)(k0 + br) * N + gc + 0] : 0.f;
        vb.y = (gc + 1 < N) ? Wz[(long)(k0 + br) * N + gc + 1] : 0.f;
        vb.z = (gc + 2 < N) ? Wz[(long)(k0 + br) * N + gc + 2] : 0.f;
        vb.w = (gc + 3 < N) ? Wz[(long)(k0 + br) * N + gc + 3] : 0.f;
      }
      *(float4*)&Bs[br][bc] = vb;
    }
    __syncthreads();
#pragma unroll
    for (int kk = 0; kk < 16; kk++) {
      float a[8], b[8];
      *(float4*)&a[0] = *(const float4*)&As[kk][ty * 8];
      *(float4*)&a[4] = *(const float4*)&As[kk][ty * 8 + 4];
      *(float4*)&b[0] = *(const float4*)&Bs[kk][tx * 8];
      *(float4*)&b[4] = *(const float4*)&Bs[kk][tx * 8 + 4];
#pragma unroll
      for (int i = 0; i < 8; i++)
#pragma unroll
        for (int j = 0; j < 8; j++) acc[i][j] = fmaf(a[i], b[j], acc[i][j]);
    }
    __syncthreads();
  }
#pragma unroll
  for (int i = 0; i < 8; i++) {
    int r = row0 + ty * 8 + i;
#pragma unroll
    for (int j = 0; j < 8; j++) {
      int c = col0 + tx * 8 + j;
      if (c < N) {
        float vv = acc[i][j] + bz[c];
        if (HASRES) vv += res[(long)r * N + c];
        if (RELU) vv = fmaxf(vv, 0.f);
        Cz[(long)r * N + c] = vv;
      }
    }
  }
}

// ============================ K=3 SAME conv + bias + relu ====================
template <int CIN>
__global__ __launch_bounds__(256) void conv3_kernel(
    const float* __restrict__ x, const float* __restrict__ w,
    const float* __restrict__ bias, float* __restrict__ out) {
  __shared__ float xs[34][CIN];
  const int b = blockIdx.y;
  const int l0 = blockIdx.x * 32;
  const int co = threadIdx.x;
  for (int idx = threadIdx.x; idx < 34 * CIN; idx += 256) {
    int r = idx / CIN, c = idx - r * CIN;
    int gl = l0 + r - 1;
    xs[r][c] = (gl >= 0 && gl < LPH) ? x[((long)b * LPH + gl) * CIN + c] : 0.f;
  }
  __syncthreads();
  float acc[32];
#pragma unroll
  for (int i = 0; i < 32; i++) acc[i] = 0.f;
  for (int kk = 0; kk < 3; kk++)
    for (int ci = 0; ci < CIN; ci++) {
      float wv = w[((long)kk * CIN + ci) * CDPC + co];
#pragma unroll
      for (int l = 0; l < 32; l++) acc[l] = fmaf(xs[l + kk][ci], wv, acc[l]);
    }
  float bv = bias[co];
#pragma unroll
  for (int l = 0; l < 32; l++)
    out[((long)b * LPH + l0 + l) * CDPC + co] = fmaxf(acc[l] + bv, 0.f);
}

// ============================ duration projection ============================
__global__ void dpout_kernel(const float* __restrict__ d2, const float* __restrict__ w,
                             const float* __restrict__ bb, float* __restrict__ out) {
  int wv = threadIdx.x >> 6, lane = threadIdx.x & 63;
  int row = blockIdx.x * 4 + wv;
  const float* xr = d2 + (long)row * CDPC;
  float s = 0.f;
  for (int c = lane; c < CDPC; c += 64) s = fmaf(xr[c], w[c], s);
#pragma unroll
  for (int off = 32; off > 0; off >>= 1) s += __shfl_down(s, off);
  if (lane == 0) out[row] = s + bb[0];
}

// ============================ length regulator ===============================
__global__ void regulator_kernel(const int* __restrict__ durations, int* __restrict__ idx,
                                 float* __restrict__ maskv) {
  __shared__ int cum[LPH];
  __shared__ int total;
  int b = blockIdx.x;
  if (threadIdx.x == 0) {
    int s = 0;
    for (int j = 0; j < LPH; j++) { s += durations[b * LPH + j]; cum[j] = s; }
    total = s;
  }
  __syncthreads();
  for (int t = threadIdx.x; t < TFR; t += blockDim.x) {
    int cnt = 0;
    for (int j = 0; j < LPH; j++) cnt += (cum[j] <= t) ? 1 : 0;
    if (cnt > LPH - 1) cnt = LPH - 1;
    idx[b * TFR + t] = cnt;
    maskv[b * TFR + t] = (t < total) ? 0.f : 1.f;  // 1 = masked
  }
}

// gather expanded states, apply valid mask, add scaled PE (f32 + bf16)
__global__ void gather_kernel(const float* __restrict__ h, const int* __restrict__ idx,
                              const float* __restrict__ maskv, const float* __restrict__ pe,
                              const float* __restrict__ alpha, float* __restrict__ y,
                              u16* __restrict__ yb) {
  long i = (long)blockIdx.x * 256 + threadIdx.x;
  if (i >= (long)BATCH * TFR * DMODEL) return;
  int d = (int)(i % DMODEL);
  long bt = i / DMODEL;
  int t = (int)(bt % TFR);
  long b = bt / TFR;
  float valid = 1.0f - maskv[bt];
  float v = h[((long)b * LPH + idx[bt]) * DMODEL + d] * valid + alpha[0] * pe[t * DMODEL + d];
  y[i] = v;
  yb[i] = f2b(v);
}

// ============================ launcher =======================================
extern "C" void kernel_launch(void* const* d_in, const int* in_sizes, int n_in,
                              void* d_out, int out_size, void* d_ws, size_t ws_size,
                              hipStream_t stream) {
  const int* phonemes = (const int*)d_in[0];
  const int* durations = (const int*)d_in[1];
  const float* embedw = (const float*)d_in[2];
  const float* alpha_enc = (const float*)d_in[3];
  const float* alpha_dec = (const float*)d_in[4];
  const float* enc_attn_w = (const float*)d_in[5];
  const float* enc_attn_b = (const float*)d_in[6];
  const float* enc_ffn_w1 = (const float*)d_in[7];
  const float* enc_ffn_b1 = (const float*)d_in[8];
  const float* enc_ffn_w2 = (const float*)d_in[9];
  const float* enc_ffn_b2 = (const float*)d_in[10];
  const float* enc_ln = (const float*)d_in[11];
  const float* dec_attn_w = (const float*)d_in[12];
  const float* dec_attn_b = (const float*)d_in[13];
  const float* dec_ffn_w1 = (const float*)d_in[14];
  const float* dec_ffn_b1 = (const float*)d_in[15];
  const float* dec_ffn_w2 = (const float*)d_in[16];
  const float* dec_ffn_b2 = (const float*)d_in[17];
  const float* dec_ln = (const float*)d_in[18];
  const float* dp_conv1_w = (const float*)d_in[19];
  const float* dp_conv1_b = (const float*)d_in[20];
  const float* dp_conv2_w = (const float*)d_in[21];
  const float* dp_conv2_b = (const float*)d_in[22];
  const float* dp_ln = (const float*)d_in[23];
  const float* dp_out_w = (const float*)d_in[24];
  const float* dp_out_b = (const float*)d_in[25];
  const float* mel_w = (const float*)d_in[26];
  const float* mel_b = (const float*)d_in[27];

  // ---- workspace map (bytes) -- total 139,329,536 < 151 MB proven ----
  char* base = (char*)d_ws;
  float* X0 = (float*)base;                    // 25,165,824  f32 residual stream
  u16* Xb = (u16*)(base + 25165824);           // 12,582,912  bf16 x
  u16* QKb = (u16*)(base + 37748736);          // 25,165,824  q, k (AOb overlays q)
  char* E = base + 62914560;                   // 33,554,432  Sb chunk / Mb / DP
  u16* Vt = (u16*)(base + 96468992);           // 16,777,216  V^T padded [32][256][S]
  u16* Wb = (u16*)(base + 113246208);          // 21,233,664  bf16 weights (per stack)
  float* Henc = (float*)(base + 134479872);    // 3,145,728   encoder output h
  float* PE = (float*)(base + 137625600);      // 1,572,864
  float* MASKD = (float*)(base + 139198464);   // 65,536
  int* IDX = (int*)(base + 139264000);         // 65,536

  u16* Sb = (u16*)E;
  u16* Mb = (u16*)E;
  float* DP1 = (float*)E;
  float* DP2 = DP1 + (size_t)2048 * CDPC;
  u16* AOb = QKb;

  u16* WAt = Wb;                 // 24 x [384][384]
  u16* W1t = Wb + 3538944;       // 6 x [1536][384]
  u16* W2t = Wb + 7077888;       // 6 x [384][1536]

  const int Me = BATCH * LPH;    // 2048
  const int Md = BATCH * TFR;    // 16384
  const long DD = 384L * 384;
  const long NXe = (long)Me * DMODEL;   // 786,432
  const long NXd = (long)Md * DMODEL;   // 6,291,456
  const long SSd = (long)TFR * TFR;     // 1,048,576
  const long SSe = (long)LPH * LPH;     // 16,384
  dim3 tb32(32, 8);

  posenc_kernel<<<(TFR * DMODEL + 255) / 256, 256, 0, stream>>>(PE);
  embed_kernel<<<(Me * DMODEL + 255) / 256, 256, 0, stream>>>(phonemes, embedw, PE, alpha_enc,
                                                              X0, Xb);
  // encoder weights -> bf16 transposed
  wconv_t<<<dim3(12, 12, 24), tb32, 0, stream>>>(enc_attn_w, WAt, 384, 384);
  wconv_t<<<dim3(48, 12, 6), tb32, 0, stream>>>(enc_ffn_w1, W1t, 384, 1536);
  wconv_t<<<dim3(12, 48, 6), tb32, 0, stream>>>(enc_ffn_w2, W2t, 1536, 384);

  // -------- phoneme encoder (x stream in X0/Xb) --------
  for (int i = 0; i < NLAYER; i++) {
    const u16* wa = WAt + (size_t)i * 4 * DD;
    const float* ab = enc_attn_b + (size_t)i * 4 * 384;
    bgemm<(FBIAS | FOB16 | FVT)><<<dim3(3, 16, 3), 256, 0, stream>>>(
        Xb, wa, ab, nullptr, QKb, Vt, 384, 384, 384, 384, 384,
        1, 0, 0, DD, 0, NXe, 0, 128);
    bgemm<(FOB16)><<<dim3(1, 1, 32), 256, 0, stream>>>(
        QKb, QKb + NXe, nullptr, nullptr, Sb, nullptr, 128, 192, 384, 384, 128,
        2, 128L * 384, 192, 128L * 384, 192, 2 * SSe, SSe, 0);
    softmax_bf16<2><<<(32 * 128) / 4, 256, 0, stream>>>(Sb, nullptr, 128);
    bgemm<(FOB16)><<<dim3(2, 1, 32), 256, 0, stream>>>(
        Sb, Vt, nullptr, nullptr, AOb, nullptr, 192, 128, 128, 128, 384,
        2, 2 * SSe, SSe, 512L * 128, 256L * 128, 128L * 384, 192, 0);
    bgemm<(FBIAS | FRES)><<<dim3(3, 16, 1), 256, 0, stream>>>(
        AOb, wa + 3 * DD, ab + 3 * 384, X0, X0, nullptr, 384, 384, 384, 384, 384,
        1, 0, 0, 0, 0, 0, 0, 0);
    ln2_kernel<<<Me, 256, 0, stream>>>(X0, enc_ln + ((size_t)(i * 2 + 0) * 2 + 0) * 384,
                                       enc_ln + ((size_t)(i * 2 + 0) * 2 + 1) * 384, 384,
                                       nullptr, Xb);
    bgemm<(FBIAS | FRELU | FOB16)><<<dim3(12, 16, 1), 256, 0, stream>>>(
        Xb, W1t + (size_t)i * 589824, enc_ffn_b1 + (size_t)i * 1536, nullptr, Mb, nullptr,
        1536, 384, 384, 384, 1536, 1, 0, 0, 0, 0, 0, 0, 0);
    bgemm<(FBIAS | FRES)><<<dim3(3, 16, 1), 256, 0, stream>>>(
        Mb, W2t + (size_t)i * 589824, enc_ffn_b2 + (size_t)i * 384, X0, X0, nullptr,
        384, 1536, 1536, 1536, 384, 1, 0, 0, 0, 0, 0, 0, 0);
    ln2_kernel<<<Me, 256, 0, stream>>>(X0, enc_ln + ((size_t)(i * 2 + 1) * 2 + 0) * 384,
                                       enc_ln + ((size_t)(i * 2 + 1) * 2 + 1) * 384, 384,
                                       (i == NLAYER - 1) ? Henc : nullptr,
                                       (i == NLAYER - 1) ? nullptr : Xb);
  }

  // -------- duration predictor (h = Henc) --------
  conv3_kernel<DMODEL><<<dim3(LPH / 32, BATCH), 256, 0, stream>>>(Henc, dp_conv1_w, dp_conv1_b, DP1);
  ln2_kernel<<<Me, 256, 0, stream>>>(DP1, dp_ln + 0 * CDPC, dp_ln + 1 * CDPC, CDPC, nullptr, nullptr);
  conv3_kernel<CDPC><<<dim3(LPH / 32, BATCH), 256, 0, stream>>>(DP1, dp_conv2_w, dp_conv2_b, DP2);
  ln2_kernel<<<Me, 256, 0, stream>>>(DP2, dp_ln + 2 * CDPC, dp_ln + 3 * CDPC, CDPC, nullptr, nullptr);
  float* durout = (float*)d_out + (size_t)Md * NMELB;
  dpout_kernel<<<Me / 4, 256, 0, stream>>>(DP2, dp_out_w, dp_out_b, durout);

  // -------- length regulator --------
  regulator_kernel<<<BATCH, 256, 0, stream>>>(durations, IDX, MASKD);
  gather_kernel<<<(int)((NXd + 255) / 256), 256, 0, stream>>>(Henc, IDX, MASKD, PE, alpha_dec,
                                                              X0, Xb);
  // decoder weights -> bf16 transposed (reuse Wb)
  wconv_t<<<dim3(12, 12, 24), tb32, 0, stream>>>(dec_attn_w, WAt, 384, 384);
  wconv_t<<<dim3(48, 12, 6), tb32, 0, stream>>>(dec_ffn_w1, W1t, 384, 1536);
  wconv_t<<<dim3(12, 48, 6), tb32, 0, stream>>>(dec_ffn_w2, W2t, 1536, 384);

  // -------- mel decoder --------
  for (int i = 0; i < NLAYER; i++) {
    const u16* wa = WAt + (size_t)i * 4 * DD;
    const float* ab = dec_attn_b + (size_t)i * 4 * 384;
    bgemm<(FBIAS | FOB16 | FVT)><<<dim3(3, 128, 3), 256, 0, stream>>>(
        Xb, wa, ab, nullptr, QKb, Vt, 384, 384, 384, 384, 384,
        1, 0, 0, DD, 0, NXd, 0, 1024);
    for (int c = 0; c < 2; c++) {
      const u16* qc = QKb + (size_t)c * 8 * TFR * DMODEL;
      const u16* kc = QKb + NXd + (size_t)c * 8 * TFR * DMODEL;
      bgemm<(FOB16)><<<dim3(8, 8, 16), 256, 0, stream>>>(
          qc, kc, nullptr, nullptr, Sb, nullptr, 1024, 192, 384, 384, 1024,
          2, (long)TFR * 384, 192, (long)TFR * 384, 192, 2 * SSd, SSd, 0);
      softmax_bf16<16><<<(16 * 1024) / 4, 256, 0, stream>>>(Sb, MASKD + (size_t)c * 8 * TFR, 1024);
      bgemm<(FOB16)><<<dim3(2, 8, 16), 256, 0, stream>>>(
          Sb, Vt + (size_t)c * 8 * 512 * TFR, nullptr, nullptr,
          AOb + (size_t)c * 8 * TFR * DMODEL, nullptr, 192, 1024, 1024, 1024, 384,
          2, 2 * SSd, SSd, 512L * TFR, 256L * TFR, (long)TFR * 384, 192, 0);
    }
    bgemm<(FBIAS | FRES)><<<dim3(3, 128, 1), 256, 0, stream>>>(
        AOb, wa + 3 * DD, ab + 3 * 384, X0, X0, nullptr, 384, 384, 384, 384, 384,
        1, 0, 0, 0, 0, 0, 0, 0);
    ln2_kernel<<<Md, 256, 0, stream>>>(X0, dec_ln + ((size_t)(i * 2 + 0) * 2 + 0) * 384,
                                       dec_ln + ((size_t)(i * 2 + 0) * 2 + 1) * 384, 384,
                                       nullptr, Xb);
    for (int hf = 0; hf < 2; hf++) {
      long off = (long)hf * 8192 * 384;
      bgemm<(FBIAS | FRELU | FOB16)><<<dim3(12, 64, 1), 256, 0, stream>>>(
          Xb + off, W1t + (size_t)i * 589824, dec_ffn_b1 + (size_t)i * 1536, nullptr, Mb, nullptr,
          1536, 384, 384, 384, 1536, 1, 0, 0, 0, 0, 0, 0, 0);
      bgemm<(FBIAS | FRES)><<<dim3(3, 64, 1), 256, 0, stream>>>(
          Mb, W2t + (size_t)i * 589824, dec_ffn_b2 + (size_t)i * 384, X0 + off, X0 + off, nullptr,
          384, 1536, 1536, 1536, 384, 1, 0, 0, 0, 0, 0, 0, 0);
    }
    ln2_kernel<<<Md, 256, 0, stream>>>(X0, dec_ln + ((size_t)(i * 2 + 1) * 2 + 0) * 384,
                                       dec_ln + ((size_t)(i * 2 + 1) * 2 + 1) * 384, 384,
                                       nullptr, (i == NLAYER - 1) ? nullptr : Xb);
  }

  // -------- mel projection (f32) --------
  gemm128<false, false><<<dim3(1, Md / 128, 1), 256, 0, stream>>>(
      X0, mel_w, mel_b, nullptr, (float*)d_out, Md, NMELB, 384, 0, 0);
}

// Round 3
// 3305.424 us; speedup vs baseline: 4.0662x; 1.1108x over previous
//
#include <hip/hip_runtime.h>
#include <math.h>

#define BATCH 16
#define LPH 128
#define TFR 1024
#define DMODEL 384
#define FDIM 1536
#define NLAYER 6
#define NMELB 80
#define CDPC 256
#define NEGV (-1e9f)

typedef unsigned short u16;
typedef __attribute__((ext_vector_type(8))) short short8;
typedef __attribute__((ext_vector_type(4))) float f32x4;

__device__ __forceinline__ float b2f(u16 u) {
  return __uint_as_float(((unsigned)u) << 16);
}
__device__ __forceinline__ u16 f2b(float f) {
  unsigned x = __float_as_uint(f);
  return (u16)((x + 0x7fffu + ((x >> 16) & 1u)) >> 16);
}

#define GLOAD16(gp, lp)                                                                   \
  __builtin_amdgcn_global_load_lds((const __attribute__((address_space(1))) void*)(gp),   \
                                   (__attribute__((address_space(3))) void*)(lp), 16, 0, 0)

#define FBIAS 1
#define FRES 2
#define FRELU 4
#define FOB16 8
#define FVT 16

// ===================== bf16 MFMA GEMM, 128x128 tile, BK=32 ===================
// C[M,N] = act(A[M,K] @ Bt[N,K]^T + bias (+res)). A,Bt bf16 row-major (k-contig).
// Per-z offsets: off = (z/zdiv)*s0 + (z%zdiv)*s1 for A,B,C. M%128==0, K%32==0.
// FVT: for z==2 (V of QKV), store transposed into VtP[(b*2+h)*256+d][s] (bf16).
template <int FL>
__global__ __launch_bounds__(256) void bgemm(
    const u16* __restrict__ A, const u16* __restrict__ Bt,
    const float* __restrict__ bias, const float* __restrict__ res,
    void* __restrict__ Cv, u16* __restrict__ VtP,
    int N, int K, int lda, int ldb, int ldc,
    int zdiv, long az0, long az1, long bz0, long bz1, long cz0, long cz1, int S) {
  __shared__ __align__(16) u16 As[4096];
  __shared__ __align__(16) u16 Bs[4096];
  const int tid = threadIdx.x;
  const int wave = tid >> 6, lane = tid & 63;
  const int wm = wave >> 1, wn = wave & 1;
  const int lrow = lane & 15, lk = lane >> 4;
  const int z = blockIdx.z;
  const int zq = z / zdiv, zr = z - zq * zdiv;
  const long offA = (long)zq * az0 + (long)zr * az1;
  const long offB = (long)zq * bz0 + (long)zr * bz1;
  const long offC = (long)zq * cz0 + (long)zr * cz1;
  const int row0 = blockIdx.y * 128;
  const int col0 = blockIdx.x * 128;

  // staging: 8 x 1KB insts per tile; wave w owns insts {2w, 2w+1} for A and B
  const int sj = wave * 2;
  const int srow = lane >> 2;        // 0..15
  const int skc = (lane & 3) * 8;    // ushort offset in k
  const u16* gA = A + offA + (long)(row0 + sj * 16 + srow) * lda + skc;
  const u16* gB = Bt + offB + (long)(col0 + sj * 16 + srow) * ldb + skc;
  u16* lA = As + sj * 512;
  u16* lB = Bs + sj * 512;
  const long ldak = 16L * lda;
  const long ldbk = 16L * ldb;

  f32x4 acc[4][4];
  const f32x4 zero4 = {0.f, 0.f, 0.f, 0.f};
#pragma unroll
  for (int i = 0; i < 4; i++)
#pragma unroll
    for (int j = 0; j < 4; j++) acc[i][j] = zero4;

  const int aoff = (wm * 64 + lrow) * 32 + lk * 8;
  const int boff = (wn * 64 + lrow) * 32 + lk * 8;

  for (int k0 = 0; k0 < K; k0 += 32) {
    GLOAD16(gA, lA);
    GLOAD16(gA + ldak, lA + 512);
    GLOAD16(gB, lB);
    GLOAD16(gB + ldbk, lB + 512);
    gA += 32; gB += 32;
    __syncthreads();   // drains vmcnt(0): staged data visible
    short8 av[4], bv[4];
#pragma unroll
    for (int mi = 0; mi < 4; mi++) av[mi] = *(const short8*)&As[aoff + mi * 512];
#pragma unroll
    for (int ni = 0; ni < 4; ni++) bv[ni] = *(const short8*)&Bs[boff + ni * 512];
#pragma unroll
    for (int mi = 0; mi < 4; mi++)
#pragma unroll
      for (int ni = 0; ni < 4; ni++)
        acc[mi][ni] = __builtin_amdgcn_mfma_f32_16x16x32_bf16(av[mi], bv[ni], acc[mi][ni], 0, 0, 0);
    __syncthreads();   // before next-iter staging overwrites LDS
  }

  const float* bz = (FL & FBIAS) ? bias + (long)z * N : nullptr;
  if ((FL & FVT) && z == 2) {
    // transposed V store: Vt[(b*2+h)*256 + d][s]
#pragma unroll
    for (int mi = 0; mi < 4; mi++) {
      long rg = row0 + wm * 64 + lk * 4 + (long)mi * 16;
      int bb = (int)(rg / S);
      int ss = (int)(rg % S);
#pragma unroll
      for (int ni = 0; ni < 4; ni++) {
        int c = col0 + wn * 64 + ni * 16 + lrow;
        int hh = c / 192, dd = c - hh * 192;
        float bi = bz[c];
        ushort4 o;
        o.x = f2b(acc[mi][ni][0] + bi);
        o.y = f2b(acc[mi][ni][1] + bi);
        o.z = f2b(acc[mi][ni][2] + bi);
        o.w = f2b(acc[mi][ni][3] + bi);
        *(ushort4*)&VtP[((long)(bb * 2 + hh) * 256 + dd) * S + ss] = o;
      }
    }
    return;
  }
  float* Cf = (float*)Cv + offC;
  u16* Cb = (u16*)Cv + offC;
  const float* resz = (FL & FRES) ? res + offC : nullptr;
#pragma unroll
  for (int mi = 0; mi < 4; mi++) {
    long rbase = row0 + wm * 64 + lk * 4 + (long)mi * 16;
#pragma unroll
    for (int ni = 0; ni < 4; ni++) {
      int c = col0 + wn * 64 + ni * 16 + lrow;
      if (c < N) {
        float bi = (FL & FBIAS) ? bz[c] : 0.f;
#pragma unroll
        for (int rr = 0; rr < 4; rr++) {
          float vv = acc[mi][ni][rr] + bi;
          if (FL & FRES) vv += resz[(rbase + rr) * (long)ldc + c];
          if (FL & FRELU) vv = fmaxf(vv, 0.f);
          if (FL & FOB16) Cb[(rbase + rr) * (long)ldc + c] = f2b(vv);
          else Cf[(rbase + rr) * (long)ldc + c] = vv;
        }
      }
    }
  }
}

// ============== weight convert+transpose: [K,N] f32 -> [N,K] bf16 ============
__global__ void wconv_t(const float* __restrict__ src, u16* __restrict__ dst, int K, int N) {
  __shared__ float t[32][33];
  long mb = blockIdx.z;
  src += mb * (long)K * N;
  dst += mb * (long)K * N;
  int n0 = blockIdx.x * 32, k0 = blockIdx.y * 32;
  int tx = threadIdx.x, ty = threadIdx.y;
#pragma unroll
  for (int i = 0; i < 4; i++) {
    int r = ty + i * 8;
    t[r][tx] = src[(long)(k0 + r) * N + n0 + tx];
  }
  __syncthreads();
#pragma unroll
  for (int i = 0; i < 4; i++) {
    int r = ty + i * 8;
    dst[(long)(n0 + r) * K + k0 + tx] = f2b(t[tx][r]);
  }
}

// ===================== softmax over bf16 score rows ==========================
// P: rows of length S (bf16, in-place). mask: [b][S] (1.0 = masked) or null.
// One wave per row, 4 rows/block. NV = S/64.
template <int NV>
__global__ __launch_bounds__(256) void softmax_bf16(u16* __restrict__ P,
                                                    const float* __restrict__ mask, int S) {
  const int wave = threadIdx.x >> 6, lane = threadIdx.x & 63;
  const long row = (long)blockIdx.x * 4 + wave;
  u16* pr = P + row * S;
  const int z = (int)(row / S);
  const float* mrow = mask ? mask + (long)(z >> 1) * S : nullptr;
  const float scale = 0.0721687836f;  // 1/sqrt(192)
  float v[NV];
  if (NV == 16) {
    short8 u0 = *(const short8*)&pr[lane * 16];
    short8 u1 = *(const short8*)&pr[lane * 16 + 8];
#pragma unroll
    for (int j = 0; j < 8; j++) {
      v[j] = b2f((u16)u0[j]);
      v[j + 8] = b2f((u16)u1[j]);
    }
  } else {
#pragma unroll
    for (int i = 0; i < NV; i++) v[i] = b2f(pr[lane * NV + i]);
  }
  float mx = -3e38f;
#pragma unroll
  for (int i = 0; i < NV; i++) {
    float mval = mrow ? mrow[lane * NV + i] * NEGV : 0.f;
    v[i] = v[i] * scale + mval;
    mx = fmaxf(mx, v[i]);
  }
  for (int off = 32; off; off >>= 1) mx = fmaxf(mx, __shfl_xor(mx, off));
  float sum = 0.f;
#pragma unroll
  for (int i = 0; i < NV; i++) {
    v[i] = __expf(v[i] - mx);
    sum += v[i];
  }
  for (int off = 32; off; off >>= 1) sum += __shfl_xor(sum, off);
  float inv = 1.f / sum;
  if (NV == 16) {
    short8 s0, s1;
#pragma unroll
    for (int j = 0; j < 8; j++) {
      s0[j] = (short)f2b(v[j] * inv);
      s1[j] = (short)f2b(v[j + 8] * inv);
    }
    *(short8*)&pr[lane * 16] = s0;
    *(short8*)&pr[lane * 16 + 8] = s1;
  } else {
#pragma unroll
    for (int i = 0; i < NV; i++) pr[lane * NV + i] = f2b(v[i] * inv);
  }
}

// ============================ positional encoding ============================
__global__ void posenc_kernel(float* __restrict__ pe) {
  int i = blockIdx.x * 256 + threadIdx.x;
  if (i >= TFR * DMODEL) return;
  int t = i / DMODEL, d = i - t * DMODEL;
  float f = (2.0f * (float)(d >> 1)) / (float)DMODEL;
  float ang = (float)t * powf(10000.0f, -f);
  pe[i] = (d & 1) ? cosf(ang) : sinf(ang);
}

// ===================== embedding + scaled PE (f32 + bf16) ====================
__global__ void embed_kernel(const int* __restrict__ ph, const float* __restrict__ emb,
                             const float* __restrict__ pe, const float* __restrict__ alpha,
                             float* __restrict__ x, u16* __restrict__ xb) {
  int i = blockIdx.x * 256 + threadIdx.x;
  if (i >= BATCH * LPH * DMODEL) return;
  int d = i % DMODEL;
  int bl = i / DMODEL;
  int l = bl % LPH;
  float v = emb[ph[bl] * DMODEL + d] + alpha[0] * pe[l * DMODEL + d];
  x[i] = v;
  xb[i] = f2b(v);
}

// ================= LayerNorm: in-place or to outf; optional bf16 =============
__global__ __launch_bounds__(256) void ln2_kernel(float* __restrict__ x,
                                                  const float* __restrict__ gamma,
                                                  const float* __restrict__ beta, int C,
                                                  float* __restrict__ outf,
                                                  u16* __restrict__ outb) {
  long row = blockIdx.x;
  float* xr = x + row * C;
  int tid = threadIdx.x;
  float e0 = 0.f, e1 = 0.f;
  float s1 = 0.f, s2 = 0.f;
  if (tid < C) { e0 = xr[tid]; s1 += e0; s2 += e0 * e0; }
  if (tid + 256 < C) { e1 = xr[tid + 256]; s1 += e1; s2 += e1 * e1; }
#pragma unroll
  for (int off = 32; off > 0; off >>= 1) {
    s1 += __shfl_down(s1, off);
    s2 += __shfl_down(s2, off);
  }
  __shared__ float w1[4], w2[4];
  if ((tid & 63) == 0) { w1[tid >> 6] = s1; w2[tid >> 6] = s2; }
  __syncthreads();
  float S1 = w1[0] + w1[1] + w1[2] + w1[3];
  float S2 = w2[0] + w2[1] + w2[2] + w2[3];
  float mean = S1 / C;
  float var = S2 / C - mean * mean;
  float rstd = rsqrtf(var + 1e-6f);
  float* tf = outf ? outf + row * C : xr;
  if (tid < C) {
    float v = (e0 - mean) * rstd * gamma[tid] + beta[tid];
    tf[tid] = v;
    if (outb) outb[row * C + tid] = f2b(v);
  }
  if (tid + 256 < C) {
    float v = (e1 - mean) * rstd * gamma[tid + 256] + beta[tid + 256];
    tf[tid + 256] = v;
    if (outb) outb[row * C + tid + 256] = f2b(v);
  }
}

// ============================ f32 tiled GEMM (mel only) ======================
template <bool RELU, bool HASRES>
__global__ __launch_bounds__(256) void gemm128(
    const float* __restrict__ A, const float* __restrict__ W,
    const float* __restrict__ bias, const float* __restrict__ res,
    float* __restrict__ C, int M, int N, int K, long wstride, long cstride) {
  __shared__ __align__(16) float As[16][128];
  __shared__ __align__(16) float Bs[16][128];
  const int tid = threadIdx.x;
  const int tx = tid & 15, ty = tid >> 4;
  const float* Wz = W + (long)blockIdx.z * wstride;
  const float* bz = bias + (long)blockIdx.z * N;
  float* Cz = C + (long)blockIdx.z * cstride;
  const int row0 = blockIdx.y * 128;
  const int col0 = blockIdx.x * 128;
  float acc[8][8];
#pragma unroll
  for (int i = 0; i < 8; i++)
#pragma unroll
    for (int j = 0; j < 8; j++) acc[i][j] = 0.f;

  for (int k0 = 0; k0 < K; k0 += 16) {
#pragma unroll
    for (int i = 0; i < 2; i++) {
      int fi = tid + i * 256;
      int ar = fi >> 2;
      int ac = (fi & 3) * 4;
      float4 va = *(const float4*)&A[(long)(row0 + ar) * K + k0 + ac];
      As[ac + 0][ar] = va.x; As[ac + 1][ar] = va.y;
      As[ac + 2][ar] = va.z; As[ac + 3][ar] = va.w;
    }
#pragma unroll
    for (int i = 0; i < 2; i++) {
      int fi = tid + i * 256;
      int br = fi >> 5;
      int bc = (fi & 31) * 4;
      int gc = col0 + bc;
      float4 vb;
      if (gc + 3 < N) {
        vb = *(const float4*)&Wz[(long)(k0 + br) * N + gc];
      } else {
        vb.x = (gc + 0 < N) ? Wz[(long)(k0 + br) * N + gc + 0] : 0.f;
        vb.y = (gc + 1 < N) ? Wz[(long)(k0 + br) * N + gc + 1] : 0.f;
        vb.z = (gc + 2 < N) ? Wz[(long)(k0 + br) * N + gc + 2] : 0.f;
        vb.w = (gc + 3 < N) ? Wz[(long)(k0 + br) * N + gc + 3] : 0.f;
      }
      *(float4*)&Bs[br][bc] = vb;
    }
    __syncthreads();
#pragma unroll
    for (int kk = 0; kk < 16; kk++) {
      float a[8], b[8];
      *(float4*)&a[0] = *(const float4*)&As[kk][ty * 8];
      *(float4*)&a[4] = *(const float4*)&As[kk][ty * 8 + 4];
      *(float4*)&b[0] = *(const float4*)&Bs[kk][tx * 8];
      *(float4*)&b[4] = *(const float4*)&Bs[kk][tx * 8 + 4];
#pragma unroll
      for (int i = 0; i < 8; i++)
#pragma unroll
        for (int j = 0; j < 8; j++) acc[i][j] = fmaf(a[i], b[j], acc[i][j]);
    }
    __syncthreads();
  }
#pragma unroll
  for (int i = 0; i < 8; i++) {
    int r = row0 + ty * 8 + i;
#pragma unroll
    for (int j = 0; j < 8; j++) {
      int c = col0 + tx * 8 + j;
      if (c < N) {
        float vv = acc[i][j] + bz[c];
        if (HASRES) vv += res[(long)r * N + c];
        if (RELU) vv = fmaxf(vv, 0.f);
        Cz[(long)r * N + c] = vv;
      }
    }
  }
}

// ==================== im2col for K=3 SAME conv (f32 -> bf16) =================
// x: [B][LPH][CIN] f32 -> a: [B*LPH][3*CIN] bf16, zero-padded at seq edges.
template <int CIN>
__global__ __launch_bounds__(256) void im2col3(const float* __restrict__ x,
                                               u16* __restrict__ a) {
  const int PER = (3 * CIN) / 8;  // 8-elem groups per output row
  long idx = (long)blockIdx.x * 256 + threadIdx.x;
  if (idx >= (long)BATCH * LPH * PER) return;
  int row = (int)(idx / PER);
  int e8 = (int)(idx - (long)row * PER) * 8;
  int kk = e8 / CIN, ci = e8 - kk * CIN;  // CIN%8==0: group stays in one tap
  int b = row >> 7, l = row & (LPH - 1);
  int gl = l + kk - 1;
  ushort4 o0 = {0, 0, 0, 0}, o1 = {0, 0, 0, 0};
  if (gl >= 0 && gl < LPH) {
    const float* src = x + ((long)(b * LPH + gl) * CIN + ci);
    float4 v0 = *(const float4*)src;
    float4 v1 = *(const float4*)(src + 4);
    o0.x = f2b(v0.x); o0.y = f2b(v0.y); o0.z = f2b(v0.z); o0.w = f2b(v0.w);
    o1.x = f2b(v1.x); o1.y = f2b(v1.y); o1.z = f2b(v1.z); o1.w = f2b(v1.w);
  }
  *(ushort4*)&a[(long)row * (3 * CIN) + e8] = o0;
  *(ushort4*)&a[(long)row * (3 * CIN) + e8 + 4] = o1;
}

// ============================ duration projection ============================
__global__ void dpout_kernel(const float* __restrict__ d2, const float* __restrict__ w,
                             const float* __restrict__ bb, float* __restrict__ out) {
  int wv = threadIdx.x >> 6, lane = threadIdx.x & 63;
  int row = blockIdx.x * 4 + wv;
  const float* xr = d2 + (long)row * CDPC;
  float s = 0.f;
  for (int c = lane; c < CDPC; c += 64) s = fmaf(xr[c], w[c], s);
#pragma unroll
  for (int off = 32; off > 0; off >>= 1) s += __shfl_down(s, off);
  if (lane == 0) out[row] = s + bb[0];
}

// ============================ length regulator ===============================
__global__ void regulator_kernel(const int* __restrict__ durations, int* __restrict__ idx,
                                 float* __restrict__ maskv) {
  __shared__ int cum[LPH];
  __shared__ int total;
  int b = blockIdx.x;
  if (threadIdx.x == 0) {
    int s = 0;
    for (int j = 0; j < LPH; j++) { s += durations[b * LPH + j]; cum[j] = s; }
    total = s;
  }
  __syncthreads();
  for (int t = threadIdx.x; t < TFR; t += blockDim.x) {
    int cnt = 0;
    for (int j = 0; j < LPH; j++) cnt += (cum[j] <= t) ? 1 : 0;
    if (cnt > LPH - 1) cnt = LPH - 1;
    idx[b * TFR + t] = cnt;
    maskv[b * TFR + t] = (t < total) ? 0.f : 1.f;  // 1 = masked
  }
}

// gather expanded states, apply valid mask, add scaled PE (f32 + bf16)
__global__ void gather_kernel(const float* __restrict__ h, const int* __restrict__ idx,
                              const float* __restrict__ maskv, const float* __restrict__ pe,
                              const float* __restrict__ alpha, float* __restrict__ y,
                              u16* __restrict__ yb) {
  long i = (long)blockIdx.x * 256 + threadIdx.x;
  if (i >= (long)BATCH * TFR * DMODEL) return;
  int d = (int)(i % DMODEL);
  long bt = i / DMODEL;
  int t = (int)(bt % TFR);
  long b = bt / TFR;
  float valid = 1.0f - maskv[bt];
  float v = h[((long)b * LPH + idx[bt]) * DMODEL + d] * valid + alpha[0] * pe[t * DMODEL + d];
  y[i] = v;
  yb[i] = f2b(v);
}

// ============================ launcher =======================================
extern "C" void kernel_launch(void* const* d_in, const int* in_sizes, int n_in,
                              void* d_out, int out_size, void* d_ws, size_t ws_size,
                              hipStream_t stream) {
  const int* phonemes = (const int*)d_in[0];
  const int* durations = (const int*)d_in[1];
  const float* embedw = (const float*)d_in[2];
  const float* alpha_enc = (const float*)d_in[3];
  const float* alpha_dec = (const float*)d_in[4];
  const float* enc_attn_w = (const float*)d_in[5];
  const float* enc_attn_b = (const float*)d_in[6];
  const float* enc_ffn_w1 = (const float*)d_in[7];
  const float* enc_ffn_b1 = (const float*)d_in[8];
  const float* enc_ffn_w2 = (const float*)d_in[9];
  const float* enc_ffn_b2 = (const float*)d_in[10];
  const float* enc_ln = (const float*)d_in[11];
  const float* dec_attn_w = (const float*)d_in[12];
  const float* dec_attn_b = (const float*)d_in[13];
  const float* dec_ffn_w1 = (const float*)d_in[14];
  const float* dec_ffn_b1 = (const float*)d_in[15];
  const float* dec_ffn_w2 = (const float*)d_in[16];
  const float* dec_ffn_b2 = (const float*)d_in[17];
  const float* dec_ln = (const float*)d_in[18];
  const float* dp_conv1_w = (const float*)d_in[19];
  const float* dp_conv1_b = (const float*)d_in[20];
  const float* dp_conv2_w = (const float*)d_in[21];
  const float* dp_conv2_b = (const float*)d_in[22];
  const float* dp_ln = (const float*)d_in[23];
  const float* dp_out_w = (const float*)d_in[24];
  const float* dp_out_b = (const float*)d_in[25];
  const float* mel_w = (const float*)d_in[26];
  const float* mel_b = (const float*)d_in[27];

  // ---- workspace map (bytes) -- total 139,329,536 < 151 MB proven ----
  char* base = (char*)d_ws;
  float* X0 = (float*)base;                    // 25,165,824  f32 residual stream
  u16* Xb = (u16*)(base + 25165824);           // 12,582,912  bf16 x
  u16* QKb = (u16*)(base + 37748736);          // 25,165,824  q, k (AOb overlays q)
  char* E = base + 62914560;                   // 33,554,432  Sb chunk / Mb / DP
  u16* Vt = (u16*)(base + 96468992);           // 16,777,216  V^T padded [32][256][S]
  u16* Wb = (u16*)(base + 113246208);          // 21,233,664  bf16 weights (per stack)
  float* Henc = (float*)(base + 134479872);    // 3,145,728   encoder output h
  float* PE = (float*)(base + 137625600);      // 1,572,864
  float* MASKD = (float*)(base + 139198464);   // 65,536
  int* IDX = (int*)(base + 139264000);         // 65,536

  u16* Sb = (u16*)E;
  u16* Mb = (u16*)E;
  u16* AOb = QKb;

  // duration-predictor overlays in E (free between encoder and decoder phases)
  float* DP1 = (float*)E;                        // 2048*256*4 = 2 MB
  float* DP2 = DP1 + (size_t)2048 * CDPC;        // 2 MB
  u16* A1 = (u16*)(E + 4 * 1024 * 1024);         // 2048*1152*2 = 4.7 MB
  u16* A2 = (u16*)(E + 9 * 1024 * 1024);         // 2048*768*2  = 3.1 MB
  u16* Wdp1 = (u16*)(E + 13 * 1024 * 1024);      // 256*1152*2
  u16* Wdp2 = (u16*)(E + 15 * 1024 * 1024);      // 256*768*2

  u16* WAt = Wb;                 // 24 x [384][384]
  u16* W1t = Wb + 3538944;       // 6 x [1536][384]
  u16* W2t = Wb + 7077888;       // 6 x [384][1536]

  const int Me = BATCH * LPH;    // 2048
  const int Md = BATCH * TFR;    // 16384
  const long DD = 384L * 384;
  const long NXe = (long)Me * DMODEL;   // 786,432
  const long NXd = (long)Md * DMODEL;   // 6,291,456
  const long SSd = (long)TFR * TFR;     // 1,048,576
  const long SSe = (long)LPH * LPH;     // 16,384
  dim3 tb32(32, 8);

  posenc_kernel<<<(TFR * DMODEL + 255) / 256, 256, 0, stream>>>(PE);
  embed_kernel<<<(Me * DMODEL + 255) / 256, 256, 0, stream>>>(phonemes, embedw, PE, alpha_enc,
                                                              X0, Xb);
  // encoder weights -> bf16 transposed
  wconv_t<<<dim3(12, 12, 24), tb32, 0, stream>>>(enc_attn_w, WAt, 384, 384);
  wconv_t<<<dim3(48, 12, 6), tb32, 0, stream>>>(enc_ffn_w1, W1t, 384, 1536);
  wconv_t<<<dim3(12, 48, 6), tb32, 0, stream>>>(enc_ffn_w2, W2t, 1536, 384);

  // -------- phoneme encoder (x stream in X0/Xb) --------
  for (int i = 0; i < NLAYER; i++) {
    const u16* wa = WAt + (size_t)i * 4 * DD;
    const float* ab = enc_attn_b + (size_t)i * 4 * 384;
    bgemm<(FBIAS | FOB16 | FVT)><<<dim3(3, 16, 3), 256, 0, stream>>>(
        Xb, wa, ab, nullptr, QKb, Vt, 384, 384, 384, 384, 384,
        1, 0, 0, DD, 0, NXe, 0, 128);
    bgemm<(FOB16)><<<dim3(1, 1, 32), 256, 0, stream>>>(
        QKb, QKb + NXe, nullptr, nullptr, Sb, nullptr, 128, 192, 384, 384, 128,
        2, 128L * 384, 192, 128L * 384, 192, 2 * SSe, SSe, 0);
    softmax_bf16<2><<<(32 * 128) / 4, 256, 0, stream>>>(Sb, nullptr, 128);
    bgemm<(FOB16)><<<dim3(2, 1, 32), 256, 0, stream>>>(
        Sb, Vt, nullptr, nullptr, AOb, nullptr, 192, 128, 128, 128, 384,
        2, 2 * SSe, SSe, 512L * 128, 256L * 128, 128L * 384, 192, 0);
    bgemm<(FBIAS | FRES)><<<dim3(3, 16, 1), 256, 0, stream>>>(
        AOb, wa + 3 * DD, ab + 3 * 384, X0, X0, nullptr, 384, 384, 384, 384, 384,
        1, 0, 0, 0, 0, 0, 0, 0);
    ln2_kernel<<<Me, 256, 0, stream>>>(X0, enc_ln + ((size_t)(i * 2 + 0) * 2 + 0) * 384,
                                       enc_ln + ((size_t)(i * 2 + 0) * 2 + 1) * 384, 384,
                                       nullptr, Xb);
    bgemm<(FBIAS | FRELU | FOB16)><<<dim3(12, 16, 1), 256, 0, stream>>>(
        Xb, W1t + (size_t)i * 589824, enc_ffn_b1 + (size_t)i * 1536, nullptr, Mb, nullptr,
        1536, 384, 384, 384, 1536, 1, 0, 0, 0, 0, 0, 0, 0);
    bgemm<(FBIAS | FRES)><<<dim3(3, 16, 1), 256, 0, stream>>>(
        Mb, W2t + (size_t)i * 589824, enc_ffn_b2 + (size_t)i * 384, X0, X0, nullptr,
        384, 1536, 1536, 1536, 384, 1, 0, 0, 0, 0, 0, 0, 0);
    ln2_kernel<<<Me, 256, 0, stream>>>(X0, enc_ln + ((size_t)(i * 2 + 1) * 2 + 0) * 384,
                                       enc_ln + ((size_t)(i * 2 + 1) * 2 + 1) * 384, 384,
                                       (i == NLAYER - 1) ? Henc : nullptr,
                                       (i == NLAYER - 1) ? nullptr : Xb);
  }

  // -------- duration predictor (h = Henc) via im2col + bf16 GEMM --------
  wconv_t<<<dim3(8, 36, 1), tb32, 0, stream>>>(dp_conv1_w, Wdp1, 1152, 256);
  wconv_t<<<dim3(8, 24, 1), tb32, 0, stream>>>(dp_conv2_w, Wdp2, 768, 256);
  im2col3<DMODEL><<<(Me * 144 + 255) / 256, 256, 0, stream>>>(Henc, A1);
  bgemm<(FBIAS | FRELU)><<<dim3(2, 16, 1), 256, 0, stream>>>(
      A1, Wdp1, dp_conv1_b, nullptr, DP1, nullptr, 256, 1152, 1152, 1152, 256,
      1, 0, 0, 0, 0, 0, 0, 0);
  ln2_kernel<<<Me, 256, 0, stream>>>(DP1, dp_ln + 0 * CDPC, dp_ln + 1 * CDPC, CDPC, nullptr, nullptr);
  im2col3<CDPC><<<(Me * 96 + 255) / 256, 256, 0, stream>>>(DP1, A2);
  bgemm<(FBIAS | FRELU)><<<dim3(2, 16, 1), 256, 0, stream>>>(
      A2, Wdp2, dp_conv2_b, nullptr, DP2, nullptr, 256, 768, 768, 768, 256,
      1, 0, 0, 0, 0, 0, 0, 0);
  ln2_kernel<<<Me, 256, 0, stream>>>(DP2, dp_ln + 2 * CDPC, dp_ln + 3 * CDPC, CDPC, nullptr, nullptr);
  float* durout = (float*)d_out + (size_t)Md * NMELB;
  dpout_kernel<<<Me / 4, 256, 0, stream>>>(DP2, dp_out_w, dp_out_b, durout);

  // -------- length regulator --------
  regulator_kernel<<<BATCH, 256, 0, stream>>>(durations, IDX, MASKD);
  gather_kernel<<<(int)((NXd + 255) / 256), 256, 0, stream>>>(Henc, IDX, MASKD, PE, alpha_dec,
                                                              X0, Xb);
  // decoder weights -> bf16 transposed (reuse Wb)
  wconv_t<<<dim3(12, 12, 24), tb32, 0, stream>>>(dec_attn_w, WAt, 384, 384);
  wconv_t<<<dim3(48, 12, 6), tb32, 0, stream>>>(dec_ffn_w1, W1t, 384, 1536);
  wconv_t<<<dim3(12, 48, 6), tb32, 0, stream>>>(dec_ffn_w2, W2t, 1536, 384);

  // -------- mel decoder --------
  for (int i = 0; i < NLAYER; i++) {
    const u16* wa = WAt + (size_t)i * 4 * DD;
    const float* ab = dec_attn_b + (size_t)i * 4 * 384;
    bgemm<(FBIAS | FOB16 | FVT)><<<dim3(3, 128, 3), 256, 0, stream>>>(
        Xb, wa, ab, nullptr, QKb, Vt, 384, 384, 384, 384, 384,
        1, 0, 0, DD, 0, NXd, 0, 1024);
    for (int c = 0; c < 2; c++) {
      const u16* qc = QKb + (size_t)c * 8 * TFR * DMODEL;
      const u16* kc = QKb + NXd + (size_t)c * 8 * TFR * DMODEL;
      bgemm<(FOB16)><<<dim3(8, 8, 16), 256, 0, stream>>>(
          qc, kc, nullptr, nullptr, Sb, nullptr, 1024, 192, 384, 384, 1024,
          2, (long)TFR * 384, 192, (long)TFR * 384, 192, 2 * SSd, SSd, 0);
      softmax_bf16<16><<<(16 * 1024) / 4, 256, 0, stream>>>(Sb, MASKD + (size_t)c * 8 * TFR, 1024);
      bgemm<(FOB16)><<<dim3(2, 8, 16), 256, 0, stream>>>(
          Sb, Vt + (size_t)c * 8 * 512 * TFR, nullptr, nullptr,
          AOb + (size_t)c * 8 * TFR * DMODEL, nullptr, 192, 1024, 1024, 1024, 384,
          2, 2 * SSd, SSd, 512L * TFR, 256L * TFR, (long)TFR * 384, 192, 0);
    }
    bgemm<(FBIAS | FRES)><<<dim3(3, 128, 1), 256, 0, stream>>>(
        AOb, wa + 3 * DD, ab + 3 * 384, X0, X0, nullptr, 384, 384, 384, 384, 384,
        1, 0, 0, 0, 0, 0, 0, 0);
    ln2_kernel<<<Md, 256, 0, stream>>>(X0, dec_ln + ((size_t)(i * 2 + 0) * 2 + 0) * 384,
                                       dec_ln + ((size_t)(i * 2 + 0) * 2 + 1) * 384, 384,
                                       nullptr, Xb);
    for (int hf = 0; hf < 2; hf++) {
      long off = (long)hf * 8192 * 384;
      bgemm<(FBIAS | FRELU | FOB16)><<<dim3(12, 64, 1), 256, 0, stream>>>(
          Xb + off, W1t + (size_t)i * 589824, dec_ffn_b1 + (size_t)i * 1536, nullptr, Mb, nullptr,
          1536, 384, 384, 384, 1536, 1, 0, 0, 0, 0, 0, 0, 0);
      bgemm<(FBIAS | FRES)><<<dim3(3, 64, 1), 256, 0, stream>>>(
          Mb, W2t + (size_t)i * 589824, dec_ffn_b2 + (size_t)i * 384, X0 + off, X0 + off, nullptr,
          384, 1536, 1536, 1536, 384, 1, 0, 0, 0, 0, 0, 0, 0);
    }
    ln2_kernel<<<Md, 256, 0, stream>>>(X0, dec_ln + ((size_t)(i * 2 + 1) * 2 + 0) * 384,
                                       dec_ln + ((size_t)(i * 2 + 1) * 2 + 1) * 384, 384,
                                       nullptr, (i == NLAYER - 1) ? nullptr : Xb);
  }

  // -------- mel projection (f32) --------
  gemm128<false, false><<<dim3(1, Md / 128, 1), 256, 0, stream>>>(
      X0, mel_w, mel_b, nullptr, (float*)d_out, Md, NMELB, 384, 0, 0);
}